// Round 2
// baseline (36836.224 us; speedup 1.0000x reference)
//
#include <hip/hip_runtime.h>
#include <hip/hip_cooperative_groups.h>

namespace cg = cooperative_groups;

#define BB 32
#define TT 500
#define HH 1612
#define HP 1664              // H padded to 8 waves * 208
#define NW 8                 // waves per workgroup
#define THREADS 512
#define NWG 256
#define RPW 8                // row slots per WG, zero-padded
#define KPW (HP / NW)        // 208 k per wave
#define ALO 1280
#define AHI 1460
#define WSTR 1668            // padded W LDS row stride (1668%32==4 -> conflict-free row broadcast)
#define RSTR 36              // padded LDS row stride for reduction buffers
#define T_CONST 0.1f

__global__ __launch_bounds__(THREADS, 1) void mrnn_kernel(
    const float* __restrict__ inp,  const float* __restrict__ cue,
    const float* __restrict__ hn,   const float* __restrict__ xn,
    const float* __restrict__ stim, const float* __restrict__ Wrec,
    const float* __restrict__ Wmask,const float* __restrict__ Wfix,
    const float* __restrict__ Wsign,const float* __restrict__ Winp,
    const float* __restrict__ Wcue, const float* __restrict__ walm,
    const float* __restrict__ base, float* __restrict__ out,
    float* __restrict__ hA,         float* __restrict__ hB)
{
    __shared__ float Wlds[RPW * WSTR];          // 53376 B, persistent W_eff slice
    __shared__ float red[NW * RPW * RSTR];      // 9216 B, cross-wave partials
    __shared__ float almb[RPW * RSTR];          // 1152 B, ALM row reduce

    const int tid  = threadIdx.x;
    const int wg   = blockIdx.x;
    const int wave = tid >> 6;
    const int lane = tid & 63;
    const int bl   = lane & 15;          // batch lane: handles b=bl and b=bl+16
    const int rq   = (lane >> 4) & 3;    // row group: handles rows rq and rq+4

    const int r0    = (wg * HH) / NWG;
    const int r1    = ((wg + 1) * HH) / NWG;
    const int nreal = r1 - r0;           // 6 or 7 real rows

    // ---- one-time: sign diagonal into LDS (aliased on red; synced before reuse) ----
    float* sdiag = red;
    for (int k = tid; k < HP; k += THREADS)
        sdiag[k] = (k < HH) ? Wsign[k * HH + k] : 0.f;
    __syncthreads();

    // ---- one-time: build W_eff slice into LDS (zero-padded rows/k) ----
    for (int r = 0; r < RPW; ++r) {
        const int j = r0 + r;
        const bool rowok = (r < nreal);
        for (int k = tid; k < HP; k += THREADS) {
            float v = 0.f;
            if (rowok && k < HH) {
                float w = Wrec[j * HH + k];
                w = fminf(fmaxf(w, 0.f), 1.f);
                v = (Wmask[j * HH + k] * w + Wfix[j * HH + k]) * sdiag[k];
            }
            Wlds[r * WSTR + k] = v;
        }
    }
    __syncthreads();

    // ---- one-time: h0 into hA in blocked [k/4][b][4] layout, zero d_out ----
    const int gtid = wg * THREADS + tid;
    for (int i = gtid; i < HP * BB; i += NWG * THREADS) {
        const int k = i >> 5, b = i & 31;
        const float v = (k < HH) ? hn[b * HH + k] : 0.f;
        hA[(k >> 2) * (BB * 4) + b * 4 + (k & 3)] = v;
    }
    for (int i = gtid; i < BB * TT; i += NWG * THREADS) out[i] = 0.f;

    // ---- epilogue-thread state (tid < 256 owns one (row, batch)) ----
    const int er = tid & 7, eb = tid >> 3;
    const int ej = r0 + er;
    const bool eactive = (tid < 256) && (er < nreal);
    float xst = 0.f, basej = 0.f, winpj = 0.f, wcuej = 0.f, walmj = 0.f;
    if (eactive) {
        xst   = xn[eb * HH + ej];
        basej = base[ej];
        winpj = Winp[ej];
        wcuej = Wcue[ej];
        walmj = (ej >= ALO && ej < AHI) ? walm[ej - ALO] : 0.f;
    }
    const bool has_alm = (r1 > ALO) && (r0 < AHI);

    cg::grid_group grid = cg::this_grid();
    grid.sync();

    const int kbase = wave * KPW;
    float* hc  = hA;
    float* hnx = hB;

    for (int t = 0; t < TT; ++t) {
        // prefetch epilogue operands; latency hides under the k-loop
        float sv = 0.f, iv = 0.f, cv = 0.f;
        if (eactive) {
            sv = stim[eb * (TT * HH) + t * HH + ej];
            iv = inp[eb * TT + t];
            cv = cue[eb * TT + t];
        }

        // ---- k-loop: 2 rows x 2 batches per lane, wave-split over K ----
        // per quad: 2 LDS b128 (row broadcast, distinct banks) + 2 global b128
        // (coalesced, 4x rq redundancy) + 16 FMA  -> 8:1 FMA:mem-instr
        float a00 = 0.f, a01 = 0.f, a10 = 0.f, a11 = 0.f;
        const float* __restrict__ hq  = hc + kbase * BB + bl * 4;
        const float* __restrict__ w0p = &Wlds[rq * WSTR + kbase];
        const float* __restrict__ w1p = w0p + 4 * WSTR;
        #pragma unroll 4
        for (int q = 0; q < KPW / 4; ++q) {
            const float4 h0 = *(const float4*)(hq + q * 128);        // b = bl
            const float4 h1 = *(const float4*)(hq + q * 128 + 64);   // b = bl+16
            const float4 w0 = *(const float4*)(w0p + q * 4);         // row rq
            const float4 w1 = *(const float4*)(w1p + q * 4);         // row rq+4
            a00 = fmaf(w0.x, h0.x, a00); a00 = fmaf(w0.y, h0.y, a00);
            a00 = fmaf(w0.z, h0.z, a00); a00 = fmaf(w0.w, h0.w, a00);
            a01 = fmaf(w0.x, h1.x, a01); a01 = fmaf(w0.y, h1.y, a01);
            a01 = fmaf(w0.z, h1.z, a01); a01 = fmaf(w0.w, h1.w, a01);
            a10 = fmaf(w1.x, h0.x, a10); a10 = fmaf(w1.y, h0.y, a10);
            a10 = fmaf(w1.z, h0.z, a10); a10 = fmaf(w1.w, h0.w, a10);
            a11 = fmaf(w1.x, h1.x, a11); a11 = fmaf(w1.y, h1.y, a11);
            a11 = fmaf(w1.z, h1.z, a11); a11 = fmaf(w1.w, h1.w, a11);
        }

        // ---- cross-wave reduction through LDS ----
        red[(wave * RPW + rq    ) * RSTR + bl     ] = a00;
        red[(wave * RPW + rq    ) * RSTR + bl + 16] = a01;
        red[(wave * RPW + rq + 4) * RSTR + bl     ] = a10;
        red[(wave * RPW + rq + 4) * RSTR + bl + 16] = a11;
        __syncthreads();

        float av = 0.f;
        if (tid < 256) {
            float ff = 0.f;
            #pragma unroll
            for (int w2 = 0; w2 < NW; ++w2)
                ff += red[(w2 * RPW + er) * RSTR + eb];
            if (eactive) {
                ff += sv;
                ff = fmaf(iv, winpj, ff);
                ff = fmaf(cv, wcuej, ff);
                xst = fmaf(T_CONST, ff - xst, xst);        // x += 0.1*(ff - x)
                const float hval = fmaxf(xst + basej, 0.f);
                hnx[(ej >> 2) * (BB * 4) + eb * 4 + (ej & 3)] = hval;
                av = hval * walmj;
            }
        }

        if (has_alm) {                       // block-uniform branch
            if (tid < 256) almb[er * RSTR + eb] = av;
            __syncthreads();
            if (tid < 32) {
                float s8 = 0.f;
                #pragma unroll
                for (int r = 0; r < RPW; ++r) s8 += almb[r * RSTR + tid];
                atomicAdd(&out[tid * TT + t], s8);
            }
        }

        __threadfence();   // make h visible across XCDs before the barrier
        grid.sync();

        float* tmp = hc; hc = hnx; hnx = tmp;
    }
}

extern "C" void kernel_launch(void* const* d_in, const int* in_sizes, int n_in,
                              void* d_out, int out_size, void* d_ws, size_t ws_size,
                              hipStream_t stream) {
    const float* inp   = (const float*)d_in[0];
    const float* cue   = (const float*)d_in[1];
    const float* hn    = (const float*)d_in[2];
    const float* xn    = (const float*)d_in[3];
    const float* stim  = (const float*)d_in[4];
    const float* Wrec  = (const float*)d_in[5];
    const float* Wmask = (const float*)d_in[6];
    const float* Wfix  = (const float*)d_in[7];
    const float* Wsign = (const float*)d_in[8];
    const float* Winp  = (const float*)d_in[9];
    const float* Wcue  = (const float*)d_in[10];
    const float* walm  = (const float*)d_in[11];
    const float* base  = (const float*)d_in[12];
    float* out = (float*)d_out;
    float* hA = (float*)d_ws;
    float* hB = hA + HP * BB;

    void* args[] = { &inp, &cue, &hn, &xn, &stim, &Wrec, &Wmask, &Wfix, &Wsign,
                     &Winp, &Wcue, &walm, &base, &out, &hA, &hB };
    hipLaunchCooperativeKernel(reinterpret_cast<void*>(mrnn_kernel),
                               dim3(NWG), dim3(THREADS), args, 0, stream);
}

// Round 4
// 5447.334 us; speedup vs baseline: 6.7622x; 6.7622x over previous
//
#include <hip/hip_runtime.h>

#define BB 32
#define TT 500
#define HH 1612
#define HP 1664              // H padded to 8 waves * 208
#define HR 1624              // W_eff row padding (>= 1612 + RPW)
#define NW 8                 // waves per step workgroup
#define THREADS 512
#define NWG 256
#define RPW 8                // row slots per WG, zero-padded
#define KPW (HP / NW)        // 208 k per wave
#define ALO 1280
#define AHI 1460
#define WSTR 1668            // padded W LDS row stride (1668%32==4)
#define RSTR 36              // padded LDS row stride for reduction buffers
#define T_CONST 0.1f

// ---------------- prologue 1: small packing jobs ----------------
__global__ void init_kernel(const float* __restrict__ hn, const float* __restrict__ xn,
                            const float* __restrict__ Wsign, float* __restrict__ out,
                            float* __restrict__ hA, float* __restrict__ xs,
                            float* __restrict__ sdiag)
{
    const int gid = blockIdx.x * blockDim.x + threadIdx.x;
    const int gsz = gridDim.x * blockDim.x;
    for (int i = gid; i < HP; i += gsz)
        sdiag[i] = (i < HH) ? Wsign[(size_t)i * HH + i] : 0.f;
    for (int i = gid; i < HP * BB; i += gsz) {
        const int k = i >> 5, b = i & 31;
        hA[(k >> 2) * (BB * 4) + b * 4 + (k & 3)] = (k < HH) ? hn[b * HH + k] : 0.f;
    }
    for (int i = gid; i < HH * BB; i += gsz) {
        const int j = i >> 5, b = i & 31;
        xs[i] = xn[b * HH + j];
    }
    for (int i = gid; i < BB * TT; i += gsz) out[i] = 0.f;
}

// ---------------- prologue 2: build W_eff = (mask*clip(W,0,1)+fixed)*sign ----------------
__global__ void weff_kernel(const float* __restrict__ Wrec, const float* __restrict__ Wmask,
                            const float* __restrict__ Wfix, const float* __restrict__ sdiag,
                            float* __restrict__ Weff)
{
    const int gid = blockIdx.x * blockDim.x + threadIdx.x;
    const int gsz = gridDim.x * blockDim.x;
    const int nq = HR * (HP / 4);
    for (int qi = gid; qi < nq; qi += gsz) {
        const int j = qi / (HP / 4);
        const int k = (qi % (HP / 4)) * 4;
        float4 v = make_float4(0.f, 0.f, 0.f, 0.f);
        if (j < HH && k < HH) {
            const float4 w = *(const float4*)&Wrec[(size_t)j * HH + k];
            const float4 m = *(const float4*)&Wmask[(size_t)j * HH + k];
            const float4 f = *(const float4*)&Wfix[(size_t)j * HH + k];
            const float4 s = *(const float4*)&sdiag[k];
            v.x = (m.x * fminf(fmaxf(w.x, 0.f), 1.f) + f.x) * s.x;
            v.y = (m.y * fminf(fmaxf(w.y, 0.f), 1.f) + f.y) * s.y;
            v.z = (m.z * fminf(fmaxf(w.z, 0.f), 1.f) + f.z) * s.z;
            v.w = (m.w * fminf(fmaxf(w.w, 0.f), 1.f) + f.w) * s.w;
        }
        *(float4*)&Weff[(size_t)j * HP + k] = v;
    }
}

// ---------------- per-step kernel ----------------
template <bool PRE>
__global__ __launch_bounds__(THREADS, 1) void step_kernel(
    const int t,
    const float* __restrict__ hc,  float* __restrict__ hnx,
    float* __restrict__ xs,        const float* __restrict__ Weff,
    const float* __restrict__ Wrec,const float* __restrict__ Wmask,
    const float* __restrict__ Wfix,const float* __restrict__ sdiag,
    const float* __restrict__ inp, const float* __restrict__ cue,
    const float* __restrict__ stim,const float* __restrict__ Winp,
    const float* __restrict__ Wcue,const float* __restrict__ walm,
    const float* __restrict__ base,float* __restrict__ out)
{
    __shared__ float Wlds[RPW * WSTR];          // 53376 B
    __shared__ float red[NW * RPW * RSTR];      // 9216 B
    __shared__ float almb[RPW * RSTR];          // 1152 B

    const int tid  = threadIdx.x;
    const int wg   = blockIdx.x;
    const int wave = tid >> 6;
    const int lane = tid & 63;
    const int bl   = lane & 15;          // batch lane: b = bl, bl+16
    const int rq   = (lane >> 4) & 3;    // row group: rows rq, rq+4

    const int r0    = (wg * HH) / NWG;
    const int r1    = ((wg + 1) * HH) / NWG;
    const int nreal = r1 - r0;           // 6 or 7 real rows

    // epilogue operands: issue loads early, consumed after the k-loop
    const int er = tid & 7, eb = tid >> 3;
    const int ej = r0 + er;
    const bool eactive = (tid < 256) && (er < nreal);
    float sv = 0.f, iv = 0.f, cv = 0.f, xv = 0.f;
    float basej = 0.f, winpj = 0.f, wcuej = 0.f, walmj = 0.f;
    if (eactive) {
        // stim is streaming read-once data: nontemporal keeps it from
        // evicting the L2-resident W slice / h working set
        sv    = __builtin_nontemporal_load(
                    &stim[(size_t)eb * (TT * HH) + (size_t)t * HH + ej]);
        iv    = inp[eb * TT + t];
        cv    = cue[eb * TT + t];
        xv    = xs[ej * BB + eb];
        basej = base[ej];
        winpj = Winp[ej];
        wcuej = Wcue[ej];
        walmj = (ej >= ALO && ej < AHI) ? walm[ej - ALO] : 0.f;
    }
    const bool has_alm = (r1 > ALO) && (r0 < AHI);

    // ---- stage this WG's 8-row W slice into LDS ----
    if constexpr (PRE) {
        for (int i = tid; i < RPW * (HP / 4); i += THREADS) {
            const int r = i / (HP / 4), k = (i % (HP / 4)) * 4;
            const float4 v = *(const float4*)&Weff[(size_t)(r0 + r) * HP + k];
            *(float4*)&Wlds[r * WSTR + k] = v;
        }
    } else {
        for (int i = tid; i < RPW * (HP / 4); i += THREADS) {
            const int r = i / (HP / 4), k = (i % (HP / 4)) * 4;
            const int j = r0 + r;
            float4 v = make_float4(0.f, 0.f, 0.f, 0.f);
            if (r < nreal && k < HH) {
                const float4 w = *(const float4*)&Wrec[(size_t)j * HH + k];
                const float4 m = *(const float4*)&Wmask[(size_t)j * HH + k];
                const float4 f = *(const float4*)&Wfix[(size_t)j * HH + k];
                const float4 s = *(const float4*)&sdiag[k];
                v.x = (m.x * fminf(fmaxf(w.x, 0.f), 1.f) + f.x) * s.x;
                v.y = (m.y * fminf(fmaxf(w.y, 0.f), 1.f) + f.y) * s.y;
                v.z = (m.z * fminf(fmaxf(w.z, 0.f), 1.f) + f.z) * s.z;
                v.w = (m.w * fminf(fmaxf(w.w, 0.f), 1.f) + f.w) * s.w;
            }
            *(float4*)&Wlds[r * WSTR + k] = v;
        }
    }
    __syncthreads();

    // ---- k-loop: 2 rows x 2 batches per lane, wave-split over K ----
    float a00 = 0.f, a01 = 0.f, a10 = 0.f, a11 = 0.f;
    {
        const int kbase = wave * KPW;
        const float* __restrict__ hq  = hc + kbase * BB + bl * 4;
        const float* __restrict__ w0p = &Wlds[rq * WSTR + kbase];
        const float* __restrict__ w1p = w0p + 4 * WSTR;
        #pragma unroll 4
        for (int q = 0; q < KPW / 4; ++q) {
            const float4 h0 = *(const float4*)(hq + q * 128);        // b = bl
            const float4 h1 = *(const float4*)(hq + q * 128 + 64);   // b = bl+16
            const float4 w0 = *(const float4*)(w0p + q * 4);         // row rq
            const float4 w1 = *(const float4*)(w1p + q * 4);         // row rq+4
            a00 = fmaf(w0.x, h0.x, a00); a00 = fmaf(w0.y, h0.y, a00);
            a00 = fmaf(w0.z, h0.z, a00); a00 = fmaf(w0.w, h0.w, a00);
            a01 = fmaf(w0.x, h1.x, a01); a01 = fmaf(w0.y, h1.y, a01);
            a01 = fmaf(w0.z, h1.z, a01); a01 = fmaf(w0.w, h1.w, a01);
            a10 = fmaf(w1.x, h0.x, a10); a10 = fmaf(w1.y, h0.y, a10);
            a10 = fmaf(w1.z, h0.z, a10); a10 = fmaf(w1.w, h0.w, a10);
            a11 = fmaf(w1.x, h1.x, a11); a11 = fmaf(w1.y, h1.y, a11);
            a11 = fmaf(w1.z, h1.z, a11); a11 = fmaf(w1.w, h1.w, a11);
        }
    }

    // ---- cross-wave reduction through LDS ----
    red[(wave * RPW + rq    ) * RSTR + bl     ] = a00;
    red[(wave * RPW + rq    ) * RSTR + bl + 16] = a01;
    red[(wave * RPW + rq + 4) * RSTR + bl     ] = a10;
    red[(wave * RPW + rq + 4) * RSTR + bl + 16] = a11;
    __syncthreads();

    float av = 0.f;
    if (tid < 256) {
        float ff = 0.f;
        #pragma unroll
        for (int w2 = 0; w2 < NW; ++w2)
            ff += red[(w2 * RPW + er) * RSTR + eb];
        if (eactive) {
            ff += sv;
            ff = fmaf(iv, winpj, ff);
            ff = fmaf(cv, wcuej, ff);
            xv = fmaf(T_CONST, ff - xv, xv);            // x += 0.1*(ff - x)
            xs[ej * BB + eb] = xv;
            const float hval = fmaxf(xv + basej, 0.f);
            hnx[(ej >> 2) * (BB * 4) + eb * 4 + (ej & 3)] = hval;
            av = hval * walmj;
        }
    }

    if (has_alm) {                       // block-uniform branch
        if (tid < 256) almb[er * RSTR + eb] = av;
        __syncthreads();
        if (tid < 32) {
            float s8 = 0.f;
            #pragma unroll
            for (int r = 0; r < RPW; ++r) s8 += almb[r * RSTR + tid];
            atomicAdd(&out[tid * TT + t], s8);
        }
    }
}

extern "C" void kernel_launch(void* const* d_in, const int* in_sizes, int n_in,
                              void* d_out, int out_size, void* d_ws, size_t ws_size,
                              hipStream_t stream) {
    const float* inp   = (const float*)d_in[0];
    const float* cue   = (const float*)d_in[1];
    const float* hn    = (const float*)d_in[2];
    const float* xn    = (const float*)d_in[3];
    const float* stim  = (const float*)d_in[4];
    const float* Wrec  = (const float*)d_in[5];
    const float* Wmask = (const float*)d_in[6];
    const float* Wfix  = (const float*)d_in[7];
    const float* Wsign = (const float*)d_in[8];
    const float* Winp  = (const float*)d_in[9];
    const float* Wcue  = (const float*)d_in[10];
    const float* walm  = (const float*)d_in[11];
    const float* base  = (const float*)d_in[12];
    float* out = (float*)d_out;

    const size_t weff_elems = (size_t)HR * HP;
    const size_t need = (weff_elems + 3 * (size_t)HP * BB + HP) * sizeof(float);
    const bool pre = (ws_size >= need);

    float* Weff, *hA, *hB, *xs, *sdiag;
    if (pre) {
        Weff  = (float*)d_ws;
        hA    = Weff + weff_elems;
    } else {
        Weff  = nullptr;
        hA    = (float*)d_ws;
    }
    hB    = hA + (size_t)HP * BB;
    xs    = hB + (size_t)HP * BB;
    sdiag = xs + (size_t)HP * BB;

    init_kernel<<<NWG, 256, 0, stream>>>(hn, xn, Wsign, out, hA, xs, sdiag);
    if (pre)
        weff_kernel<<<NWG, 256, 0, stream>>>(Wrec, Wmask, Wfix, sdiag, Weff);

    float* hc = hA;
    float* hx = hB;
    for (int t = 0; t < TT; ++t) {
        if (pre)
            step_kernel<true><<<NWG, THREADS, 0, stream>>>(
                t, hc, hx, xs, Weff, nullptr, nullptr, nullptr, nullptr,
                inp, cue, stim, Winp, Wcue, walm, base, out);
        else
            step_kernel<false><<<NWG, THREADS, 0, stream>>>(
                t, hc, hx, xs, nullptr, Wrec, Wmask, Wfix, sdiag,
                inp, cue, stim, Winp, Wcue, walm, base, out);
        float* tmp = hc; hc = hx; hx = tmp;
    }
}

// Round 5
// 5138.757 us; speedup vs baseline: 7.1683x; 1.0600x over previous
//
#include <hip/hip_runtime.h>

#define BB 32
#define TT 500
#define HH 1612
#define HP 1664              // H padded to 8 waves * 208
#define HR 1624              // W_eff row padding (fallback path)
#define NW 8                 // waves per workgroup
#define THREADS 512
#define NWG 256
#define RPW 8                // row slots per WG, zero-padded
#define KPW (HP / NW)        // 208 k per wave
#define ALO 1280
#define AHI 1460
#define WSTR 1668            // padded W LDS row stride (1668%32==4)
#define RSTR 36              // padded LDS row stride for reduction buffers
#define HBUF (HP * BB)       // 53248 floats per h buffer
#define T_CONST 0.1f

// ================= persistent path =================

__global__ void pers_init(const float* __restrict__ hn, const float* __restrict__ Wsign,
                          float* __restrict__ out, float* __restrict__ hbase,
                          float* __restrict__ sdiag, unsigned* __restrict__ cnt)
{
    const int gid = blockIdx.x * blockDim.x + threadIdx.x;
    const int gsz = gridDim.x * blockDim.x;
    for (int i = gid; i < HP; i += gsz)
        sdiag[i] = (i < HH) ? Wsign[(size_t)i * HH + i] : 0.f;
    // buffer 0: pack h0 into blocked [k/4][b][4] layout (zero pad)
    for (int i = gid; i < HP * BB; i += gsz) {
        const int k = i >> 5, b = i & 31;
        hbase[(k >> 2) * 128 + b * 4 + (k & 3)] = (k < HH) ? hn[b * HH + k] : 0.f;
    }
    // buffers 1..TT: zero the k-padding tail (floats [403*128, 416*128))
    for (int i = gid; i < TT * 13 * 128; i += gsz) {
        const int buf = 1 + i / (13 * 128);
        const int off = i % (13 * 128);
        hbase[(size_t)buf * HBUF + 403 * 128 + off] = 0.f;
    }
    for (int i = gid; i < BB * TT; i += gsz) out[i] = 0.f;
    for (int i = gid; i < 512; i += gsz) cnt[i] = 0u;
}

__global__ __launch_bounds__(THREADS, 1) void pers_kernel(
    const float* __restrict__ xn,
    const float* __restrict__ Wrec, const float* __restrict__ Wmask,
    const float* __restrict__ Wfix, const float* __restrict__ sdiag,
    const float* __restrict__ inp,  const float* __restrict__ cue,
    const float* __restrict__ stim, const float* __restrict__ Winp,
    const float* __restrict__ Wcue, const float* __restrict__ walm,
    const float* __restrict__ base, float* __restrict__ out,
    float* __restrict__ hbase,      unsigned* __restrict__ cnt)
{
    __shared__ float Wlds[RPW * WSTR];          // 53376 B, persistent W_eff slice
    __shared__ float red[NW * RPW * RSTR];      // 9216 B
    __shared__ float almb[RPW * RSTR];          // 1152 B

    const int tid  = threadIdx.x;
    const int wg   = blockIdx.x;
    const int wave = tid >> 6;
    const int lane = tid & 63;
    const int bl   = lane & 15;          // batch lane: b = bl, bl+16
    const int rq   = (lane >> 4) & 3;    // row group: rows rq, rq+4

    const int r0    = (wg * HH) / NWG;
    const int r1    = ((wg + 1) * HH) / NWG;
    const int nreal = r1 - r0;

    // ---- one-time: build W_eff slice into LDS ----
    for (int i = tid; i < RPW * (HP / 4); i += THREADS) {
        const int r = i / (HP / 4), k = (i % (HP / 4)) * 4;
        const int j = r0 + r;
        float4 v = make_float4(0.f, 0.f, 0.f, 0.f);
        if (r < nreal && k < HH) {
            const float4 w = *(const float4*)&Wrec[(size_t)j * HH + k];
            const float4 m = *(const float4*)&Wmask[(size_t)j * HH + k];
            const float4 f = *(const float4*)&Wfix[(size_t)j * HH + k];
            const float4 s = *(const float4*)&sdiag[k];
            v.x = (m.x * fminf(fmaxf(w.x, 0.f), 1.f) + f.x) * s.x;
            v.y = (m.y * fminf(fmaxf(w.y, 0.f), 1.f) + f.y) * s.y;
            v.z = (m.z * fminf(fmaxf(w.z, 0.f), 1.f) + f.z) * s.z;
            v.w = (m.w * fminf(fmaxf(w.w, 0.f), 1.f) + f.w) * s.w;
        }
        *(float4*)&Wlds[r * WSTR + k] = v;
    }

    // ---- persistent epilogue state in registers ----
    const int er = tid & 7, eb = tid >> 3;
    const int ej = r0 + er;
    const bool eactive = (tid < 256) && (er < nreal);
    float xv = 0.f, basej = 0.f, winpj = 0.f, wcuej = 0.f, walmj = 0.f;
    if (eactive) {
        xv    = xn[eb * HH + ej];
        basej = base[ej];
        winpj = Winp[ej];
        wcuej = Wcue[ej];
        walmj = (ej >= ALO && ej < AHI) ? walm[ej - ALO] : 0.f;
    }
    const bool has_alm = (r1 > ALO) && (r0 < AHI);
    const int kbase = wave * KPW;

    __syncthreads();

    for (int t = 0; t < TT; ++t) {
        const float* __restrict__ hc = hbase + (size_t)t * HBUF;
        float* __restrict__ hx       = hbase + (size_t)(t + 1) * HBUF;

        float sv = 0.f, iv = 0.f, cv = 0.f;
        if (eactive) {
            sv = __builtin_nontemporal_load(
                     &stim[(size_t)eb * (TT * HH) + (size_t)t * HH + ej]);
            iv = inp[eb * TT + t];
            cv = cue[eb * TT + t];
        }

        // ---- k-loop: 2 rows x 2 batches per lane, wave-split over K ----
        float a00 = 0.f, a01 = 0.f, a10 = 0.f, a11 = 0.f;
        {
            const float* __restrict__ hq  = hc + kbase * BB + bl * 4;
            const float* __restrict__ w0p = &Wlds[rq * WSTR + kbase];
            const float* __restrict__ w1p = w0p + 4 * WSTR;
            #pragma unroll 4
            for (int q = 0; q < KPW / 4; ++q) {
                const float4 h0 = *(const float4*)(hq + q * 128);
                const float4 h1 = *(const float4*)(hq + q * 128 + 64);
                const float4 w0 = *(const float4*)(w0p + q * 4);
                const float4 w1 = *(const float4*)(w1p + q * 4);
                a00 = fmaf(w0.x, h0.x, a00); a00 = fmaf(w0.y, h0.y, a00);
                a00 = fmaf(w0.z, h0.z, a00); a00 = fmaf(w0.w, h0.w, a00);
                a01 = fmaf(w0.x, h1.x, a01); a01 = fmaf(w0.y, h1.y, a01);
                a01 = fmaf(w0.z, h1.z, a01); a01 = fmaf(w0.w, h1.w, a01);
                a10 = fmaf(w1.x, h0.x, a10); a10 = fmaf(w1.y, h0.y, a10);
                a10 = fmaf(w1.z, h0.z, a10); a10 = fmaf(w1.w, h0.w, a10);
                a11 = fmaf(w1.x, h1.x, a11); a11 = fmaf(w1.y, h1.y, a11);
                a11 = fmaf(w1.z, h1.z, a11); a11 = fmaf(w1.w, h1.w, a11);
            }
        }

        // ---- cross-wave reduction through LDS ----
        red[(wave * RPW + rq    ) * RSTR + bl     ] = a00;
        red[(wave * RPW + rq    ) * RSTR + bl + 16] = a01;
        red[(wave * RPW + rq + 4) * RSTR + bl     ] = a10;
        red[(wave * RPW + rq + 4) * RSTR + bl + 16] = a11;
        __syncthreads();

        float av = 0.f;
        if (tid < 256) {
            float ff = 0.f;
            #pragma unroll
            for (int w2 = 0; w2 < NW; ++w2)
                ff += red[(w2 * RPW + er) * RSTR + eb];
            if (eactive) {
                ff += sv;
                ff = fmaf(iv, winpj, ff);
                ff = fmaf(cv, wcuej, ff);
                xv = fmaf(T_CONST, ff - xv, xv);
                const float hval = fmaxf(xv + basej, 0.f);
                // commit h at LLC (no dirty L2/L1 line anywhere)
                __hip_atomic_store(&hx[(ej >> 2) * 128 + eb * 4 + (ej & 3)], hval,
                                   __ATOMIC_RELAXED, __HIP_MEMORY_SCOPE_AGENT);
                av = hval * walmj;
            }
        }

        if (has_alm) {                       // block-uniform branch
            if (tid < 256) almb[er * RSTR + eb] = av;
            __syncthreads();
            if (tid < 32) {
                float s8 = 0.f;
                #pragma unroll
                for (int r = 0; r < RPW; ++r) s8 += almb[r * RSTR + tid];
                atomicAdd(&out[tid * TT + t], s8);
            }
        }

        // ---- grid barrier: no cache maintenance needed (fresh buffers) ----
        if (t != TT - 1) {
            __syncthreads();   // drains each wave's vmcnt (h stores committed)
            if (tid == 0)
                __hip_atomic_fetch_add(&cnt[(wg & 7) << 6], 1u,
                                       __ATOMIC_RELAXED, __HIP_MEMORY_SCOPE_AGENT);
            if (wave == 0) {
                const unsigned target = 256u * (unsigned)(t + 1);
                unsigned s;
                do {
                    unsigned v = (lane < 8)
                        ? __hip_atomic_load(&cnt[lane << 6], __ATOMIC_RELAXED,
                                            __HIP_MEMORY_SCOPE_AGENT)
                        : 0u;
                    v += __shfl_xor(v, 1);
                    v += __shfl_xor(v, 2);
                    v += __shfl_xor(v, 4);
                    s = __shfl(v, 0);
                } while (s < target);
            }
            __syncthreads();
        }
    }
}

// ================= fallback path (round-4, proven) =================

__global__ void init_kernel(const float* __restrict__ hn, const float* __restrict__ xn,
                            const float* __restrict__ Wsign, float* __restrict__ out,
                            float* __restrict__ hA, float* __restrict__ xs,
                            float* __restrict__ sdiag)
{
    const int gid = blockIdx.x * blockDim.x + threadIdx.x;
    const int gsz = gridDim.x * blockDim.x;
    for (int i = gid; i < HP; i += gsz)
        sdiag[i] = (i < HH) ? Wsign[(size_t)i * HH + i] : 0.f;
    for (int i = gid; i < HP * BB; i += gsz) {
        const int k = i >> 5, b = i & 31;
        hA[(k >> 2) * (BB * 4) + b * 4 + (k & 3)] = (k < HH) ? hn[b * HH + k] : 0.f;
    }
    for (int i = gid; i < HH * BB; i += gsz) {
        const int j = i >> 5, b = i & 31;
        xs[i] = xn[b * HH + j];
    }
    for (int i = gid; i < BB * TT; i += gsz) out[i] = 0.f;
}

__global__ void weff_kernel(const float* __restrict__ Wrec, const float* __restrict__ Wmask,
                            const float* __restrict__ Wfix, const float* __restrict__ sdiag,
                            float* __restrict__ Weff)
{
    const int gid = blockIdx.x * blockDim.x + threadIdx.x;
    const int gsz = gridDim.x * blockDim.x;
    const int nq = HR * (HP / 4);
    for (int qi = gid; qi < nq; qi += gsz) {
        const int j = qi / (HP / 4);
        const int k = (qi % (HP / 4)) * 4;
        float4 v = make_float4(0.f, 0.f, 0.f, 0.f);
        if (j < HH && k < HH) {
            const float4 w = *(const float4*)&Wrec[(size_t)j * HH + k];
            const float4 m = *(const float4*)&Wmask[(size_t)j * HH + k];
            const float4 f = *(const float4*)&Wfix[(size_t)j * HH + k];
            const float4 s = *(const float4*)&sdiag[k];
            v.x = (m.x * fminf(fmaxf(w.x, 0.f), 1.f) + f.x) * s.x;
            v.y = (m.y * fminf(fmaxf(w.y, 0.f), 1.f) + f.y) * s.y;
            v.z = (m.z * fminf(fmaxf(w.z, 0.f), 1.f) + f.z) * s.z;
            v.w = (m.w * fminf(fmaxf(w.w, 0.f), 1.f) + f.w) * s.w;
        }
        *(float4*)&Weff[(size_t)j * HP + k] = v;
    }
}

template <bool PRE>
__global__ __launch_bounds__(THREADS, 1) void step_kernel(
    const int t,
    const float* __restrict__ hc,  float* __restrict__ hnx,
    float* __restrict__ xs,        const float* __restrict__ Weff,
    const float* __restrict__ Wrec,const float* __restrict__ Wmask,
    const float* __restrict__ Wfix,const float* __restrict__ sdiag,
    const float* __restrict__ inp, const float* __restrict__ cue,
    const float* __restrict__ stim,const float* __restrict__ Winp,
    const float* __restrict__ Wcue,const float* __restrict__ walm,
    const float* __restrict__ base,float* __restrict__ out)
{
    __shared__ float Wlds[RPW * WSTR];
    __shared__ float red[NW * RPW * RSTR];
    __shared__ float almb[RPW * RSTR];

    const int tid  = threadIdx.x;
    const int wg   = blockIdx.x;
    const int wave = tid >> 6;
    const int lane = tid & 63;
    const int bl   = lane & 15;
    const int rq   = (lane >> 4) & 3;

    const int r0    = (wg * HH) / NWG;
    const int r1    = ((wg + 1) * HH) / NWG;
    const int nreal = r1 - r0;

    const int er = tid & 7, eb = tid >> 3;
    const int ej = r0 + er;
    const bool eactive = (tid < 256) && (er < nreal);
    float sv = 0.f, iv = 0.f, cv = 0.f, xv = 0.f;
    float basej = 0.f, winpj = 0.f, wcuej = 0.f, walmj = 0.f;
    if (eactive) {
        sv    = __builtin_nontemporal_load(
                    &stim[(size_t)eb * (TT * HH) + (size_t)t * HH + ej]);
        iv    = inp[eb * TT + t];
        cv    = cue[eb * TT + t];
        xv    = xs[ej * BB + eb];
        basej = base[ej];
        winpj = Winp[ej];
        wcuej = Wcue[ej];
        walmj = (ej >= ALO && ej < AHI) ? walm[ej - ALO] : 0.f;
    }
    const bool has_alm = (r1 > ALO) && (r0 < AHI);

    if constexpr (PRE) {
        for (int i = tid; i < RPW * (HP / 4); i += THREADS) {
            const int r = i / (HP / 4), k = (i % (HP / 4)) * 4;
            const float4 v = *(const float4*)&Weff[(size_t)(r0 + r) * HP + k];
            *(float4*)&Wlds[r * WSTR + k] = v;
        }
    } else {
        for (int i = tid; i < RPW * (HP / 4); i += THREADS) {
            const int r = i / (HP / 4), k = (i % (HP / 4)) * 4;
            const int j = r0 + r;
            float4 v = make_float4(0.f, 0.f, 0.f, 0.f);
            if (r < nreal && k < HH) {
                const float4 w = *(const float4*)&Wrec[(size_t)j * HH + k];
                const float4 m = *(const float4*)&Wmask[(size_t)j * HH + k];
                const float4 f = *(const float4*)&Wfix[(size_t)j * HH + k];
                const float4 s = *(const float4*)&sdiag[k];
                v.x = (m.x * fminf(fmaxf(w.x, 0.f), 1.f) + f.x) * s.x;
                v.y = (m.y * fminf(fmaxf(w.y, 0.f), 1.f) + f.y) * s.y;
                v.z = (m.z * fminf(fmaxf(w.z, 0.f), 1.f) + f.z) * s.z;
                v.w = (m.w * fminf(fmaxf(w.w, 0.f), 1.f) + f.w) * s.w;
            }
            *(float4*)&Wlds[r * WSTR + k] = v;
        }
    }
    __syncthreads();

    float a00 = 0.f, a01 = 0.f, a10 = 0.f, a11 = 0.f;
    {
        const int kbase = wave * KPW;
        const float* __restrict__ hq  = hc + kbase * BB + bl * 4;
        const float* __restrict__ w0p = &Wlds[rq * WSTR + kbase];
        const float* __restrict__ w1p = w0p + 4 * WSTR;
        #pragma unroll 4
        for (int q = 0; q < KPW / 4; ++q) {
            const float4 h0 = *(const float4*)(hq + q * 128);
            const float4 h1 = *(const float4*)(hq + q * 128 + 64);
            const float4 w0 = *(const float4*)(w0p + q * 4);
            const float4 w1 = *(const float4*)(w1p + q * 4);
            a00 = fmaf(w0.x, h0.x, a00); a00 = fmaf(w0.y, h0.y, a00);
            a00 = fmaf(w0.z, h0.z, a00); a00 = fmaf(w0.w, h0.w, a00);
            a01 = fmaf(w0.x, h1.x, a01); a01 = fmaf(w0.y, h1.y, a01);
            a01 = fmaf(w0.z, h1.z, a01); a01 = fmaf(w0.w, h1.w, a01);
            a10 = fmaf(w1.x, h0.x, a10); a10 = fmaf(w1.y, h0.y, a10);
            a10 = fmaf(w1.z, h0.z, a10); a10 = fmaf(w1.w, h0.w, a10);
            a11 = fmaf(w1.x, h1.x, a11); a11 = fmaf(w1.y, h1.y, a11);
            a11 = fmaf(w1.z, h1.z, a11); a11 = fmaf(w1.w, h1.w, a11);
        }
    }

    red[(wave * RPW + rq    ) * RSTR + bl     ] = a00;
    red[(wave * RPW + rq    ) * RSTR + bl + 16] = a01;
    red[(wave * RPW + rq + 4) * RSTR + bl     ] = a10;
    red[(wave * RPW + rq + 4) * RSTR + bl + 16] = a11;
    __syncthreads();

    float av = 0.f;
    if (tid < 256) {
        float ff = 0.f;
        #pragma unroll
        for (int w2 = 0; w2 < NW; ++w2)
            ff += red[(w2 * RPW + er) * RSTR + eb];
        if (eactive) {
            ff += sv;
            ff = fmaf(iv, winpj, ff);
            ff = fmaf(cv, wcuej, ff);
            xv = fmaf(T_CONST, ff - xv, xv);
            xs[ej * BB + eb] = xv;
            const float hval = fmaxf(xv + basej, 0.f);
            hnx[(ej >> 2) * (BB * 4) + eb * 4 + (ej & 3)] = hval;
            av = hval * walmj;
        }
    }

    if (has_alm) {
        if (tid < 256) almb[er * RSTR + eb] = av;
        __syncthreads();
        if (tid < 32) {
            float s8 = 0.f;
            #pragma unroll
            for (int r = 0; r < RPW; ++r) s8 += almb[r * RSTR + tid];
            atomicAdd(&out[tid * TT + t], s8);
        }
    }
}

extern "C" void kernel_launch(void* const* d_in, const int* in_sizes, int n_in,
                              void* d_out, int out_size, void* d_ws, size_t ws_size,
                              hipStream_t stream) {
    const float* inp   = (const float*)d_in[0];
    const float* cue   = (const float*)d_in[1];
    const float* hn    = (const float*)d_in[2];
    const float* xn    = (const float*)d_in[3];
    const float* stim  = (const float*)d_in[4];
    const float* Wrec  = (const float*)d_in[5];
    const float* Wmask = (const float*)d_in[6];
    const float* Wfix  = (const float*)d_in[7];
    const float* Wsign = (const float*)d_in[8];
    const float* Winp  = (const float*)d_in[9];
    const float* Wcue  = (const float*)d_in[10];
    const float* walm  = (const float*)d_in[11];
    const float* base  = (const float*)d_in[12];
    float* out = (float*)d_out;

    // ---- persistent path: (TT+1) h buffers + sdiag + counters ----
    const size_t pers_need = ((size_t)(TT + 1) * HBUF + HP) * sizeof(float) + 2048;
    if (ws_size >= pers_need) {
        float* hbase    = (float*)d_ws;
        float* sdiag    = hbase + (size_t)(TT + 1) * HBUF;
        unsigned* cnt   = (unsigned*)(sdiag + HP);

        pers_init<<<NWG, 256, 0, stream>>>(hn, Wsign, out, hbase, sdiag, cnt);

        void* args[] = { (void*)&xn, (void*)&Wrec, (void*)&Wmask, (void*)&Wfix,
                         (void*)&sdiag, (void*)&inp, (void*)&cue, (void*)&stim,
                         (void*)&Winp, (void*)&Wcue, (void*)&walm, (void*)&base,
                         (void*)&out, (void*)&hbase, (void*)&cnt };
        hipLaunchCooperativeKernel(reinterpret_cast<void*>(pers_kernel),
                                   dim3(NWG), dim3(THREADS), args, 0, stream);
        return;
    }

    // ---- fallback: proven 500-step-kernel path ----
    const size_t weff_elems = (size_t)HR * HP;
    const size_t need = (weff_elems + 3 * (size_t)HP * BB + HP) * sizeof(float);
    const bool pre = (ws_size >= need);

    float* Weff, *hA, *hB, *xs, *sdiag;
    if (pre) {
        Weff  = (float*)d_ws;
        hA    = Weff + weff_elems;
    } else {
        Weff  = nullptr;
        hA    = (float*)d_ws;
    }
    hB    = hA + (size_t)HP * BB;
    xs    = hB + (size_t)HP * BB;
    sdiag = xs + (size_t)HP * BB;

    init_kernel<<<NWG, 256, 0, stream>>>(hn, xn, Wsign, out, hA, xs, sdiag);
    if (pre)
        weff_kernel<<<NWG, 256, 0, stream>>>(Wrec, Wmask, Wfix, sdiag, Weff);

    float* hc = hA;
    float* hx = hB;
    for (int t = 0; t < TT; ++t) {
        if (pre)
            step_kernel<true><<<NWG, THREADS, 0, stream>>>(
                t, hc, hx, xs, Weff, nullptr, nullptr, nullptr, nullptr,
                inp, cue, stim, Winp, Wcue, walm, base, out);
        else
            step_kernel<false><<<NWG, THREADS, 0, stream>>>(
                t, hc, hx, xs, nullptr, Wrec, Wmask, Wfix, sdiag,
                inp, cue, stim, Winp, Wcue, walm, base, out);
        float* tmp = hc; hc = hx; hx = tmp;
    }
}